// Round 10
// baseline (457.283 us; speedup 1.0000x reference)
//
#include <hip/hip_runtime.h>
#include <hip/hip_bf16.h>
#include <cstdint>
#include <cstddef>

// MoE expert FFN: h = gelu(x @ w1[e]^T + b1[e]); out = h @ w2[e]^T + b2[e]
// R10: R8 locked core (128x128 / 4-wave / BK=32 / 2-buffer, T2 swizzle,
// fast-gelu, natural order, 16x16x32 MFMA) + ONE new mechanism:
//   K-LOOP PHASE ROTATION: block starts its K sweep at phase = f(bx,mt) % nk
//   and wraps. De-phases co-resident blocks' staging bursts (they otherwise
//   barrier in lockstep -> synchronized HBM/L2 bursts with idle gaps; cross-
//   block overlap needs blocks at DIFFERENT phases). f32 acc is order-indep.
// + split-K=2 on GEMM2 (2 -> 4 blocks/CU so de-phasing has overlap partners)
//   with f32 combine pass (psum overlays dead w1_bf).

typedef __bf16 bf16x8 __attribute__((ext_vector_type(8)));
typedef float f32x4 __attribute__((ext_vector_type(4)));
typedef unsigned short u16x8 __attribute__((ext_vector_type(8)));

#define BM 128
#define BN 128
#define BK 32

__device__ __forceinline__ unsigned short f2bf(float f) {
  unsigned u = __builtin_bit_cast(unsigned, f);
  u += 0x7FFFu + ((u >> 16) & 1u);   // RNE
  return (unsigned short)(u >> 16);
}

__device__ __forceinline__ float fast_gelu(float v) {
  const float u = 0.7978845608028654f * (v + 0.044715f * v * v * v);
  const float t = 1.0f - 2.0f / (__expf(2.0f * u) + 1.0f);   // tanh(u)
  return 0.5f * v * (1.0f + t);
}

__device__ __forceinline__ void gload16(const void* g, void* lds) {
  __builtin_amdgcn_global_load_lds(
      (const __attribute__((address_space(1))) void*)g,
      (__attribute__((address_space(3))) void*)lds, 16, 0, 0);
}

// ---------------- setup: tile table (BM=128, shared) -------------------------
__global__ void build_tiles(const int* __restrict__ cnt, int E,
                            int4* __restrict__ tbl, int* __restrict__ ntp) {
  if (threadIdx.x == 0 && blockIdx.x == 0) {
    int nt = 0, start = 0;
    for (int e = 0; e < E; ++e) {
      int c = cnt[e];
      for (int t = 0; t < c; t += BM) {
        int4 v; v.x = e; v.y = start + t; v.z = (c - t < BM ? c - t : BM); v.w = 0;
        tbl[nt++] = v;
      }
      start += c;
    }
    *ntp = nt;
  }
}

// ---------------- f32 -> bf16 convert (vectorized) ---------------------------
__global__ void cvt_kernel(const float* __restrict__ src,
                           unsigned short* __restrict__ dst, long n) {
  long i = ((long)blockIdx.x * blockDim.x + threadIdx.x) * 8;
  const long stride = (long)gridDim.x * blockDim.x * 8;
  for (; i < n; i += stride) {
    float4 a = *reinterpret_cast<const float4*>(src + i);
    float4 b = *reinterpret_cast<const float4*>(src + i + 4);
    u16x8 o;
    o[0] = f2bf(a.x); o[1] = f2bf(a.y); o[2] = f2bf(a.z); o[3] = f2bf(a.w);
    o[4] = f2bf(b.x); o[5] = f2bf(b.y); o[6] = f2bf(b.z); o[7] = f2bf(b.w);
    *reinterpret_cast<u16x8*>(dst + i) = o;
  }
}

// ---------------- split-K combine: out = p0 + p1 (bias already in p0) --------
__global__ void combine_kernel(const float* __restrict__ p0,
                               const float* __restrict__ p1,
                               float* __restrict__ out, long n) {
  long i = ((long)blockIdx.x * blockDim.x + threadIdx.x) * 4;
  const long stride = (long)gridDim.x * blockDim.x * 4;
  for (; i < n; i += stride) {
    float4 a = *reinterpret_cast<const float4*>(p0 + i);
    float4 b = *reinterpret_cast<const float4*>(p1 + i);
    float4 o; o.x = a.x + b.x; o.y = a.y + b.y; o.z = a.z + b.z; o.w = a.w + b.w;
    *reinterpret_cast<float4*>(out + i) = o;
  }
}

// ---------------- grouped GEMM (R8 core + K-phase rotation) ------------------
// C[t,n] = A[t, ks*Kloc:(ks+1)*Kloc] . W[e][n, same] (+bias at ks==0, opt gelu)
template <int GELU, int OUTBF, int SPLITK>
__global__ __launch_bounds__(256, 2) void grouped_gemm(
    const unsigned short* __restrict__ A, const unsigned short* __restrict__ W,
    const float* __restrict__ bias, void* __restrict__ Cv,
    const int4* __restrict__ tbl, const int* __restrict__ ntp,
    const int N, const int K, const int Ttot) {
  const int ks = (SPLITK > 1) ? blockIdx.z : 0;
  const int Kloc = K / SPLITK;

  const int mt = blockIdx.y;
  const int bx = blockIdx.x;
  if (mt >= *ntp) return;
  const int4 ti = tbl[mt];
  const int e = ti.x, row0 = ti.y, rows = ti.z;
  const int bcol = bx * BN;

  __shared__ alignas(16) unsigned short sA[2][BM * BK];
  __shared__ alignas(16) unsigned short sB[2][BN * BK];

  const int tid = threadIdx.x;
  const int lane = tid & 63;
  const int wave = tid >> 6;
  const int wr = wave >> 1;  // 0..1
  const int wc = wave & 1;   // 0..1
  const int lr = lane & 15;
  const int lhi = lane >> 4; // 0..3

  const unsigned short* __restrict__ Aseg = A + (size_t)ks * Kloc;
  const unsigned short* __restrict__ Wexp =
      W + (size_t)e * N * K + (size_t)ks * Kloc;

  // Staging (R8): dest row = wave*16 + (lane>>2) (+i*64), dest chunk = lane&3;
  // LDS byte = wave*1024 + lane*16 (linear). Source chunk pre-swizzled
  // (dest ^ ((row>>1)&3), thread-constant).
  const int srow = wave * 16 + (lane >> 2);   // + i*64
  const int cg = (lane & 3) ^ ((srow >> 1) & 3);
  const int a0 = srow < rows ? srow : rows - 1;
  const int a1 = srow + 64 < rows ? srow + 64 : rows - 1;
  const unsigned short* gA0 = Aseg + (size_t)(row0 + a0) * K + cg * 8;
  const unsigned short* gA1 = Aseg + (size_t)(row0 + a1) * K + cg * 8;
  const unsigned short* gB0 = Wexp + (size_t)(bcol + srow) * K + cg * 8;
  const unsigned short* gB1 = Wexp + (size_t)(bcol + srow + 64) * K + cg * 8;

  auto stage = [&](int kt, int b) {
    const int k0 = kt * BK;
    char* da = (char*)&sA[b][0] + wave * 1024;
    char* db = (char*)&sB[b][0] + wave * 1024;
    gload16(gA0 + k0, da);
    gload16(gA1 + k0, da + 4096);
    gload16(gB0 + k0, db);
    gload16(gB1 + k0, db + 4096);
  };

  f32x4 acc[4][4] = {};
  const int aRowB = wr * 64 + lr;
  const int bRowB = wc * 64 + lr;
  const int rsw = (lhi ^ ((lr >> 1) & 3)) * 8;   // read-side swizzle (R2: 0 cfl)

  const int nk = Kloc / BK;
  // K-phase rotation: per-block start offset, wraps mod nk.
  const int phase = (bx * 29 + mt * 17 + ks * 11) % nk;

  stage(phase, 0);
  __syncthreads();

  int buf = 0;
  int k = phase;
  for (int t = 0; t < nk; ++t) {
    const int kn = (k + 1 == nk) ? 0 : k + 1;
    if (t + 1 < nk) stage(kn, buf ^ 1);
    bf16x8 af[4], bfr[4];
#pragma unroll
    for (int m = 0; m < 4; ++m)
      af[m] = *reinterpret_cast<const bf16x8*>(&sA[buf][(aRowB + m * 16) * BK + rsw]);
#pragma unroll
    for (int n = 0; n < 4; ++n)
      bfr[n] = *reinterpret_cast<const bf16x8*>(&sB[buf][(bRowB + n * 16) * BK + rsw]);
#pragma unroll
    for (int m = 0; m < 4; ++m)
#pragma unroll
      for (int n = 0; n < 4; ++n)
        acc[m][n] = __builtin_amdgcn_mfma_f32_16x16x32_bf16(af[m], bfr[n], acc[m][n], 0, 0, 0);
    __syncthreads();
    buf ^= 1;
    k = kn;
  }

  // Epilogue. C/D layout (m89): col = lane&15, row = (lane>>4)*4 + reg.
  const float* __restrict__ be = bias + (size_t)e * N;
  float* __restrict__ outF = (float*)Cv + (size_t)ks * Ttot * N;
  const int colBase = bcol + wc * 64 + lr;
  const int rowBase = wr * 64 + (lhi << 2);
#pragma unroll
  for (int n = 0; n < 4; ++n) {
    const int col = colBase + n * 16;
    const float bv = (SPLITK == 1 || ks == 0) ? be[col] : 0.0f;
#pragma unroll
    for (int m = 0; m < 4; ++m) {
      const int r0 = rowBase + m * 16;
#pragma unroll
      for (int j = 0; j < 4; ++j) {
        const int rr = r0 + j;
        if (rr < rows) {
          float v = acc[m][n][j] + bv;
          if (GELU) v = fast_gelu(v);
          const size_t idx = (size_t)(row0 + rr) * N + col;
          if (OUTBF) ((unsigned short*)Cv)[idx] = f2bf(v);
          else       outF[idx] = v;
        }
      }
    }
  }
}

extern "C" void kernel_launch(void* const* d_in, const int* in_sizes, int n_in,
                              void* d_out, int out_size, void* d_ws, size_t ws_size,
                              hipStream_t stream) {
  const float* inp = (const float*)d_in[0];
  const float* w1  = (const float*)d_in[1];
  const float* b1  = (const float*)d_in[2];
  const float* w2  = (const float*)d_in[3];
  const float* b2  = (const float*)d_in[4];
  const int*   cnt = (const int*)d_in[5];

  const int E = in_sizes[5];
  const int H = in_sizes[2] / E;       // b1 is [E,H]
  const int D = in_sizes[4] / E;       // b2 is [E,D]
  const int T = in_sizes[0] / D;       // inp is [T,D]

  char* ws = (char*)d_ws;
  int4* tbl = (int4*)ws;               // <= 72 entries
  int* ntp = (int*)(ws + 2048);
  size_t off = 4096;
  unsigned short* inp_bf = (unsigned short*)(ws + off); off += (size_t)T * D * 2;
  unsigned short* w1_bf  = (unsigned short*)(ws + off); off += (size_t)E * H * D * 2;
  unsigned short* w2_bf  = (unsigned short*)(ws + off); off += (size_t)E * D * H * 2;
  unsigned short* h_bf   = (unsigned short*)(ws + off); off += (size_t)T * H * 2;
  // psum (2 x T*D f32 = 64 MB) overlays w1_bf (64 MB, dead after GEMM1).
  float* psum = (float*)w1_bf;
  (void)ws_size; (void)n_in; (void)out_size;

  build_tiles<<<1, 64, 0, stream>>>(cnt, E, tbl, ntp);

  cvt_kernel<<<2048, 256, 0, stream>>>(inp, inp_bf, (long)T * D);
  cvt_kernel<<<2048, 256, 0, stream>>>(w1, w1_bf, (long)E * H * D);
  cvt_kernel<<<2048, 256, 0, stream>>>(w2, w2_bf, (long)E * D * H);

  const int maxTiles = T / BM + E;
  // GEMM1: [T,D] x [E,H,D] -> h [T,H], +b1, fast-gelu, bf16 out.
  dim3 g1(H / BN, maxTiles, 1);
  grouped_gemm<1, 1, 1><<<g1, 256, 0, stream>>>(inp_bf, w1_bf, b1, h_bf,
                                                tbl, ntp, H, D, T);
  // GEMM2: [T,H] x [E,D,H] -> psum[2][T,D] (bias in ks=0), split-K=2.
  dim3 g2(D / BN, maxTiles, 2);
  grouped_gemm<0, 0, 2><<<g2, 256, 0, stream>>>(h_bf, w2_bf, b2, psum,
                                                tbl, ntp, D, H, T);
  // out = psum0 + psum1
  combine_kernel<<<2048, 256, 0, stream>>>(psum, psum + (size_t)T * D,
                                           (float*)d_out, (long)T * D);
}

// Round 11
// 366.541 us; speedup vs baseline: 1.2476x; 1.2476x over previous
//
#include <hip/hip_runtime.h>
#include <hip/hip_bf16.h>
#include <cstdint>
#include <cstddef>

// MoE expert FFN: h = gelu(x @ w1[e]^T + b1[e]); out = h @ w2[e]^T + b2[e]
// R11: R8-exact core everywhere (128x128 / 4-wave / BK=32 / 2-buffer, swizzle,
// fast-gelu, natural block order, 16x16x32 MFMA). ONE isolated change:
//   GEMM2 split-K=2 (512 -> 1024 real blocks; GEMM2 was hard-capped at
//   2 blocks/CU by its grid size — co-residency probe, un-confounded this
//   time: no chunking, no phase tricks). psum overlays dead w1_bf; +combine.
// GEMM1 is the unchanged control (expect ~146us).

typedef __bf16 bf16x8 __attribute__((ext_vector_type(8)));
typedef float f32x4 __attribute__((ext_vector_type(4)));
typedef unsigned short u16x8 __attribute__((ext_vector_type(8)));

#define BM 128
#define BN 128
#define BK 32

__device__ __forceinline__ unsigned short f2bf(float f) {
  unsigned u = __builtin_bit_cast(unsigned, f);
  u += 0x7FFFu + ((u >> 16) & 1u);   // RNE
  return (unsigned short)(u >> 16);
}

__device__ __forceinline__ float fast_gelu(float v) {
  const float u = 0.7978845608028654f * (v + 0.044715f * v * v * v);
  const float t = 1.0f - 2.0f / (__expf(2.0f * u) + 1.0f);   // tanh(u)
  return 0.5f * v * (1.0f + t);
}

__device__ __forceinline__ void gload16(const void* g, void* lds) {
  __builtin_amdgcn_global_load_lds(
      (const __attribute__((address_space(1))) void*)g,
      (__attribute__((address_space(3))) void*)lds, 16, 0, 0);
}

// ---------------- setup: tile table (BM=128, shared) -------------------------
__global__ void build_tiles(const int* __restrict__ cnt, int E,
                            int4* __restrict__ tbl, int* __restrict__ ntp) {
  if (threadIdx.x == 0 && blockIdx.x == 0) {
    int nt = 0, start = 0;
    for (int e = 0; e < E; ++e) {
      int c = cnt[e];
      for (int t = 0; t < c; t += BM) {
        int4 v; v.x = e; v.y = start + t; v.z = (c - t < BM ? c - t : BM); v.w = 0;
        tbl[nt++] = v;
      }
      start += c;
    }
    *ntp = nt;
  }
}

// ---------------- f32 -> bf16 convert (vectorized) ---------------------------
__global__ void cvt_kernel(const float* __restrict__ src,
                           unsigned short* __restrict__ dst, long n) {
  long i = ((long)blockIdx.x * blockDim.x + threadIdx.x) * 8;
  const long stride = (long)gridDim.x * blockDim.x * 8;
  for (; i < n; i += stride) {
    float4 a = *reinterpret_cast<const float4*>(src + i);
    float4 b = *reinterpret_cast<const float4*>(src + i + 4);
    u16x8 o;
    o[0] = f2bf(a.x); o[1] = f2bf(a.y); o[2] = f2bf(a.z); o[3] = f2bf(a.w);
    o[4] = f2bf(b.x); o[5] = f2bf(b.y); o[6] = f2bf(b.z); o[7] = f2bf(b.w);
    *reinterpret_cast<u16x8*>(dst + i) = o;
  }
}

// ---------------- split-K combine: out = p0 + p1 (bias already in p0) --------
__global__ void combine_kernel(const float* __restrict__ p0,
                               const float* __restrict__ p1,
                               float* __restrict__ out, long n) {
  long i = ((long)blockIdx.x * blockDim.x + threadIdx.x) * 4;
  const long stride = (long)gridDim.x * blockDim.x * 4;
  for (; i < n; i += stride) {
    float4 a = *reinterpret_cast<const float4*>(p0 + i);
    float4 b = *reinterpret_cast<const float4*>(p1 + i);
    float4 o; o.x = a.x + b.x; o.y = a.y + b.y; o.z = a.z + b.z; o.w = a.w + b.w;
    *reinterpret_cast<float4*>(out + i) = o;
  }
}

// ---------------- grouped GEMM (R8 core) -------------------------------------
// C[t,n] = A[t, ks*Kloc:(ks+1)*Kloc] . W[e][n, same] (+bias at ks==0, opt gelu)
template <int GELU, int OUTBF, int SPLITK>
__global__ __launch_bounds__(256, 4) void grouped_gemm(
    const unsigned short* __restrict__ A, const unsigned short* __restrict__ W,
    const float* __restrict__ bias, void* __restrict__ Cv,
    const int4* __restrict__ tbl, const int* __restrict__ ntp,
    const int N, const int K, const int Ttot) {
  const int ks = (SPLITK > 1) ? blockIdx.z : 0;
  const int Kloc = K / SPLITK;

  const int mt = blockIdx.y;
  const int bx = blockIdx.x;
  if (mt >= *ntp) return;
  const int4 ti = tbl[mt];
  const int e = ti.x, row0 = ti.y, rows = ti.z;
  const int bcol = bx * BN;

  __shared__ alignas(16) unsigned short sA[2][BM * BK];
  __shared__ alignas(16) unsigned short sB[2][BN * BK];

  const int tid = threadIdx.x;
  const int lane = tid & 63;
  const int wave = tid >> 6;
  const int wr = wave >> 1;  // 0..1
  const int wc = wave & 1;   // 0..1
  const int lr = lane & 15;
  const int lhi = lane >> 4; // 0..3

  const unsigned short* __restrict__ Aseg = A + (size_t)ks * Kloc;
  const unsigned short* __restrict__ Wexp =
      W + (size_t)e * N * K + (size_t)ks * Kloc;

  // Staging (R8): dest row = wave*16 + (lane>>2) (+i*64), dest chunk = lane&3;
  // LDS byte = wave*1024 + lane*16 (linear). Source chunk pre-swizzled
  // (dest ^ ((row>>1)&3), thread-constant).
  const int srow = wave * 16 + (lane >> 2);   // + i*64
  const int cg = (lane & 3) ^ ((srow >> 1) & 3);
  const int a0 = srow < rows ? srow : rows - 1;
  const int a1 = srow + 64 < rows ? srow + 64 : rows - 1;
  const unsigned short* gA0 = Aseg + (size_t)(row0 + a0) * K + cg * 8;
  const unsigned short* gA1 = Aseg + (size_t)(row0 + a1) * K + cg * 8;
  const unsigned short* gB0 = Wexp + (size_t)(bcol + srow) * K + cg * 8;
  const unsigned short* gB1 = Wexp + (size_t)(bcol + srow + 64) * K + cg * 8;

  f32x4 acc[4][4] = {};
  const int aRowB = wr * 64 + lr;
  const int bRowB = wc * 64 + lr;
  const int rsw = (lhi ^ ((lr >> 1) & 3)) * 8;   // read-side swizzle (R2: 0 cfl)

  const int nk = Kloc / BK;

  // prologue stage into buf 0
  {
    char* da = (char*)&sA[0][0] + wave * 1024;
    char* db = (char*)&sB[0][0] + wave * 1024;
    gload16(gA0, da);
    gload16(gA1, da + 4096);
    gload16(gB0, db);
    gload16(gB1, db + 4096);
  }
  __syncthreads();

  int buf = 0;
  for (int t = 0; t < nk; ++t) {
    if (t + 1 < nk) {
      const int k0 = (t + 1) * BK;
      char* da = (char*)&sA[buf ^ 1][0] + wave * 1024;
      char* db = (char*)&sB[buf ^ 1][0] + wave * 1024;
      gload16(gA0 + k0, da);
      gload16(gA1 + k0, da + 4096);
      gload16(gB0 + k0, db);
      gload16(gB1 + k0, db + 4096);
    }
    bf16x8 af[4], bfr[4];
#pragma unroll
    for (int m = 0; m < 4; ++m)
      af[m] = *reinterpret_cast<const bf16x8*>(&sA[buf][(aRowB + m * 16) * BK + rsw]);
#pragma unroll
    for (int n = 0; n < 4; ++n)
      bfr[n] = *reinterpret_cast<const bf16x8*>(&sB[buf][(bRowB + n * 16) * BK + rsw]);
#pragma unroll
    for (int m = 0; m < 4; ++m)
#pragma unroll
      for (int n = 0; n < 4; ++n)
        acc[m][n] = __builtin_amdgcn_mfma_f32_16x16x32_bf16(af[m], bfr[n], acc[m][n], 0, 0, 0);
    __syncthreads();
    buf ^= 1;
  }

  // Epilogue. C/D layout (m89): col = lane&15, row = (lane>>4)*4 + reg.
  const float* __restrict__ be = bias + (size_t)e * N;
  float* __restrict__ outF = (float*)Cv + (size_t)ks * Ttot * N;
  const int colBase = bcol + wc * 64 + lr;
  const int rowBase = wr * 64 + (lhi << 2);
#pragma unroll
  for (int n = 0; n < 4; ++n) {
    const int col = colBase + n * 16;
    const float bv = (SPLITK == 1 || ks == 0) ? be[col] : 0.0f;
#pragma unroll
    for (int m = 0; m < 4; ++m) {
      const int r0 = rowBase + m * 16;
#pragma unroll
      for (int j = 0; j < 4; ++j) {
        const int rr = r0 + j;
        if (rr < rows) {
          float v = acc[m][n][j] + bv;
          if (GELU) v = fast_gelu(v);
          const size_t idx = (size_t)(row0 + rr) * N + col;
          if (OUTBF) ((unsigned short*)Cv)[idx] = f2bf(v);
          else       outF[idx] = v;
        }
      }
    }
  }
}

extern "C" void kernel_launch(void* const* d_in, const int* in_sizes, int n_in,
                              void* d_out, int out_size, void* d_ws, size_t ws_size,
                              hipStream_t stream) {
  const float* inp = (const float*)d_in[0];
  const float* w1  = (const float*)d_in[1];
  const float* b1  = (const float*)d_in[2];
  const float* w2  = (const float*)d_in[3];
  const float* b2  = (const float*)d_in[4];
  const int*   cnt = (const int*)d_in[5];

  const int E = in_sizes[5];
  const int H = in_sizes[2] / E;       // b1 is [E,H]
  const int D = in_sizes[4] / E;       // b2 is [E,D]
  const int T = in_sizes[0] / D;       // inp is [T,D]

  char* ws = (char*)d_ws;
  int4* tbl = (int4*)ws;               // <= 72 entries
  int* ntp = (int*)(ws + 2048);
  size_t off = 4096;
  unsigned short* inp_bf = (unsigned short*)(ws + off); off += (size_t)T * D * 2;
  unsigned short* w1_bf  = (unsigned short*)(ws + off); off += (size_t)E * H * D * 2;
  unsigned short* w2_bf  = (unsigned short*)(ws + off); off += (size_t)E * D * H * 2;
  unsigned short* h_bf   = (unsigned short*)(ws + off); off += (size_t)T * H * 2;
  // psum (2 x T*D f32 = 64 MB) overlays w1_bf (64 MB, dead after GEMM1).
  float* psum = (float*)w1_bf;
  (void)ws_size; (void)n_in; (void)out_size;

  build_tiles<<<1, 64, 0, stream>>>(cnt, E, tbl, ntp);

  cvt_kernel<<<2048, 256, 0, stream>>>(inp, inp_bf, (long)T * D);
  cvt_kernel<<<2048, 256, 0, stream>>>(w1, w1_bf, (long)E * H * D);
  cvt_kernel<<<2048, 256, 0, stream>>>(w2, w2_bf, (long)E * D * H);

  const int maxTiles = T / BM + E;
  // GEMM1 (control, R8-exact): [T,D] x [E,H,D] -> h [T,H], +b1, gelu, bf16.
  dim3 g1(H / BN, maxTiles, 1);
  grouped_gemm<1, 1, 1><<<g1, 256, 0, stream>>>(inp_bf, w1_bf, b1, h_bf,
                                                tbl, ntp, H, D, T);
  // GEMM2 (probe): split-K=2, natural order -> psum[2][T,D] (bias in ks=0).
  dim3 g2(D / BN, maxTiles, 2);
  grouped_gemm<0, 0, 2><<<g2, 256, 0, stream>>>(h_bf, w2_bf, b2, psum,
                                                tbl, ntp, D, H, T);
  // out = psum0 + psum1
  combine_kernel<<<2048, 256, 0, stream>>>(psum, psum + (size_t)T * D,
                                           (float*)d_out, (long)T * D);
}

// Round 12
// 330.905 us; speedup vs baseline: 1.3819x; 1.1077x over previous
//
#include <hip/hip_runtime.h>
#include <hip/hip_bf16.h>
#include <cstdint>
#include <cstddef>

// MoE expert FFN: h = gelu(x @ w1[e]^T + b1[e]); out = h @ w2[e]^T + b2[e]
// R12: R8 locked config (best measured: 349us) + cvt-pipeline overlap:
//   - cvt(w2) is NOT needed until GEMM2 -> piggyback it into GEMM1's dispatch
//     as 256 extra blocks (grid-y extension, branch at top). GEMM1 runs at
//     19-33% HBM, so the 192MB conversion streams in its idle bandwidth.
//   - cvt(inp) + cvt(w1) merged into one 2-segment dispatch (GEMM1 deps,
//     must precede it).
//   - GEMM core R8-exact: 128x128 / 4-wave / BK=32 / 2-buffer syncthreads,
//     T2 swizzle (0 conflicts), fast-gelu, natural order, 16x16x32 MFMA.
// 11 rounds of evidence: every schedule/shape/residency axis ties at ~146us
// per GEMM (470 TF) — consistent with the m97-family shape curve at our
// per-expert sizes (M=1024, cold single-pass weights). This is that family's
// floor; remaining recoverable time was the serial cvt work.

typedef __bf16 bf16x8 __attribute__((ext_vector_type(8)));
typedef float f32x4 __attribute__((ext_vector_type(4)));
typedef unsigned short u16x8 __attribute__((ext_vector_type(8)));

#define BM 128
#define BN 128
#define BK 32

__device__ __forceinline__ unsigned short f2bf(float f) {
  unsigned u = __builtin_bit_cast(unsigned, f);
  u += 0x7FFFu + ((u >> 16) & 1u);   // RNE
  return (unsigned short)(u >> 16);
}

__device__ __forceinline__ float fast_gelu(float v) {
  const float u = 0.7978845608028654f * (v + 0.044715f * v * v * v);
  const float t = 1.0f - 2.0f / (__expf(2.0f * u) + 1.0f);   // tanh(u)
  return 0.5f * v * (1.0f + t);
}

__device__ __forceinline__ void gload16(const void* g, void* lds) {
  __builtin_amdgcn_global_load_lds(
      (const __attribute__((address_space(1))) void*)g,
      (__attribute__((address_space(3))) void*)lds, 16, 0, 0);
}

__device__ __forceinline__ void cvt8(const float* __restrict__ src,
                                     unsigned short* __restrict__ dst, long i) {
  float4 a = *reinterpret_cast<const float4*>(src + i);
  float4 b = *reinterpret_cast<const float4*>(src + i + 4);
  u16x8 o;
  o[0] = f2bf(a.x); o[1] = f2bf(a.y); o[2] = f2bf(a.z); o[3] = f2bf(a.w);
  o[4] = f2bf(b.x); o[5] = f2bf(b.y); o[6] = f2bf(b.z); o[7] = f2bf(b.w);
  *reinterpret_cast<u16x8*>(dst + i) = o;
}

// ---------------- setup: tile table (BM=128, shared) -------------------------
__global__ void build_tiles(const int* __restrict__ cnt, int E,
                            int4* __restrict__ tbl, int* __restrict__ ntp) {
  if (threadIdx.x == 0 && blockIdx.x == 0) {
    int nt = 0, start = 0;
    for (int e = 0; e < E; ++e) {
      int c = cnt[e];
      for (int t = 0; t < c; t += BM) {
        int4 v; v.x = e; v.y = start + t; v.z = (c - t < BM ? c - t : BM); v.w = 0;
        tbl[nt++] = v;
      }
      start += c;
    }
    *ntp = nt;
  }
}

// ---------------- 2-segment f32 -> bf16 convert ------------------------------
__global__ void cvt2_kernel(const float* __restrict__ s0,
                            unsigned short* __restrict__ d0, long n0,
                            const float* __restrict__ s1,
                            unsigned short* __restrict__ d1, long n1) {
  long i = ((long)blockIdx.x * blockDim.x + threadIdx.x) * 8;
  const long stride = (long)gridDim.x * blockDim.x * 8;
  const long ntot = n0 + n1;
  for (; i < ntot; i += stride) {
    if (i < n0) cvt8(s0, d0, i);
    else        cvt8(s1, d1, i - n0);
  }
}

// ---------------- grouped GEMM (R8 core + optional cvt piggyback) ------------
// C[t,n] = A[t,:] . W[e][n,:] (+bias, opt gelu). A:[T,K] bf16, W:[E,N,K] bf16.
// PIGGY: blocks with blockIdx.y >= yTiles stream pg_src f32 -> pg_dst bf16.
template <int GELU, int OUTBF, int PIGGY>
__global__ __launch_bounds__(256, 4) void grouped_gemm(
    const unsigned short* __restrict__ A, const unsigned short* __restrict__ W,
    const float* __restrict__ bias, void* __restrict__ Cv,
    const int4* __restrict__ tbl, const int* __restrict__ ntp,
    const int N, const int K,
    const float* __restrict__ pg_src, unsigned short* __restrict__ pg_dst,
    const long pg_n, const int yTiles) {
  if (PIGGY && (int)blockIdx.y >= yTiles) {
    // cvt piggyback: runs in GEMM1's idle bandwidth; must finish within this
    // dispatch (stream order guarantees completion before GEMM2 launches).
    const int p = ((int)blockIdx.y - yTiles) * gridDim.x + blockIdx.x;
    const long PB = (long)(gridDim.y - yTiles) * gridDim.x;
    long i = ((long)p * blockDim.x + threadIdx.x) * 8;
    const long stride = PB * blockDim.x * 8;
    for (; i < pg_n; i += stride) cvt8(pg_src, pg_dst, i);
    return;
  }

  const int mt = blockIdx.y;
  const int bx = blockIdx.x;
  if (mt >= *ntp) return;
  const int4 ti = tbl[mt];
  const int e = ti.x, row0 = ti.y, rows = ti.z;
  const int bcol = bx * BN;

  __shared__ alignas(16) unsigned short sA[2][BM * BK];
  __shared__ alignas(16) unsigned short sB[2][BN * BK];

  const int tid = threadIdx.x;
  const int lane = tid & 63;
  const int wave = tid >> 6;
  const int wr = wave >> 1;  // 0..1
  const int wc = wave & 1;   // 0..1
  const int lr = lane & 15;
  const int lhi = lane >> 4; // 0..3

  const unsigned short* __restrict__ Wexp = W + (size_t)e * N * K;

  // Staging (R8): dest row = wave*16 + (lane>>2) (+i*64), dest chunk = lane&3;
  // LDS byte = wave*1024 + lane*16 (linear). Source chunk pre-swizzled
  // (dest ^ ((row>>1)&3), thread-constant).
  const int srow = wave * 16 + (lane >> 2);   // + i*64
  const int cg = (lane & 3) ^ ((srow >> 1) & 3);
  const int a0 = srow < rows ? srow : rows - 1;
  const int a1 = srow + 64 < rows ? srow + 64 : rows - 1;
  const unsigned short* gA0 = A + (size_t)(row0 + a0) * K + cg * 8;
  const unsigned short* gA1 = A + (size_t)(row0 + a1) * K + cg * 8;
  const unsigned short* gB0 = Wexp + (size_t)(bcol + srow) * K + cg * 8;
  const unsigned short* gB1 = Wexp + (size_t)(bcol + srow + 64) * K + cg * 8;

  f32x4 acc[4][4] = {};
  const int aRowB = wr * 64 + lr;
  const int bRowB = wc * 64 + lr;
  const int rsw = (lhi ^ ((lr >> 1) & 3)) * 8;   // read-side swizzle (R2: 0 cfl)

  const int nk = K / BK;

  // prologue stage into buf 0
  {
    char* da = (char*)&sA[0][0] + wave * 1024;
    char* db = (char*)&sB[0][0] + wave * 1024;
    gload16(gA0, da);
    gload16(gA1, da + 4096);
    gload16(gB0, db);
    gload16(gB1, db + 4096);
  }
  __syncthreads();

  int buf = 0;
  for (int t = 0; t < nk; ++t) {
    if (t + 1 < nk) {
      const int k0 = (t + 1) * BK;
      char* da = (char*)&sA[buf ^ 1][0] + wave * 1024;
      char* db = (char*)&sB[buf ^ 1][0] + wave * 1024;
      gload16(gA0 + k0, da);
      gload16(gA1 + k0, da + 4096);
      gload16(gB0 + k0, db);
      gload16(gB1 + k0, db + 4096);
    }
    bf16x8 af[4], bfr[4];
#pragma unroll
    for (int m = 0; m < 4; ++m)
      af[m] = *reinterpret_cast<const bf16x8*>(&sA[buf][(aRowB + m * 16) * BK + rsw]);
#pragma unroll
    for (int n = 0; n < 4; ++n)
      bfr[n] = *reinterpret_cast<const bf16x8*>(&sB[buf][(bRowB + n * 16) * BK + rsw]);
#pragma unroll
    for (int m = 0; m < 4; ++m)
#pragma unroll
      for (int n = 0; n < 4; ++n)
        acc[m][n] = __builtin_amdgcn_mfma_f32_16x16x32_bf16(af[m], bfr[n], acc[m][n], 0, 0, 0);
    __syncthreads();
    buf ^= 1;
  }

  // Epilogue. C/D layout (m89): col = lane&15, row = (lane>>4)*4 + reg.
  const float* __restrict__ be = bias + (size_t)e * N;
  const int colBase = bcol + wc * 64 + lr;
  const int rowBase = wr * 64 + (lhi << 2);
#pragma unroll
  for (int n = 0; n < 4; ++n) {
    const int col = colBase + n * 16;
    const float bv = be[col];
#pragma unroll
    for (int m = 0; m < 4; ++m) {
      const int r0 = rowBase + m * 16;
#pragma unroll
      for (int j = 0; j < 4; ++j) {
        const int rr = r0 + j;
        if (rr < rows) {
          float v = acc[m][n][j] + bv;
          if (GELU) v = fast_gelu(v);
          const size_t idx = (size_t)(row0 + rr) * N + col;
          if (OUTBF) ((unsigned short*)Cv)[idx] = f2bf(v);
          else       ((float*)Cv)[idx] = v;
        }
      }
    }
  }
}

extern "C" void kernel_launch(void* const* d_in, const int* in_sizes, int n_in,
                              void* d_out, int out_size, void* d_ws, size_t ws_size,
                              hipStream_t stream) {
  const float* inp = (const float*)d_in[0];
  const float* w1  = (const float*)d_in[1];
  const float* b1  = (const float*)d_in[2];
  const float* w2  = (const float*)d_in[3];
  const float* b2  = (const float*)d_in[4];
  const int*   cnt = (const int*)d_in[5];

  const int E = in_sizes[5];
  const int H = in_sizes[2] / E;       // b1 is [E,H]
  const int D = in_sizes[4] / E;       // b2 is [E,D]
  const int T = in_sizes[0] / D;       // inp is [T,D]

  char* ws = (char*)d_ws;
  int4* tbl = (int4*)ws;               // <= 72 entries
  int* ntp = (int*)(ws + 2048);
  size_t off = 4096;
  unsigned short* inp_bf = (unsigned short*)(ws + off); off += (size_t)T * D * 2;
  unsigned short* w1_bf  = (unsigned short*)(ws + off); off += (size_t)E * H * D * 2;
  unsigned short* w2_bf  = (unsigned short*)(ws + off); off += (size_t)E * D * H * 2;
  unsigned short* h_bf   = (unsigned short*)(ws + off); off += (size_t)T * H * 2;
  (void)ws_size; (void)n_in; (void)out_size;

  build_tiles<<<1, 64, 0, stream>>>(cnt, E, tbl, ntp);

  // cvt(inp) + cvt(w1): GEMM1 dependencies, one dispatch.
  cvt2_kernel<<<2048, 256, 0, stream>>>(inp, inp_bf, (long)T * D,
                                        w1, w1_bf, (long)E * H * D);

  const int maxTiles = T / BM + E;
  // GEMM1: [T,D] x [E,H,D] -> h [T,H], +b1, fast-gelu, bf16 out.
  // + piggyback cvt(w2) in 8 extra y-rows (256 blocks) using idle BW.
  dim3 g1(H / BN, maxTiles + 8);
  grouped_gemm<1, 1, 1><<<g1, 256, 0, stream>>>(
      inp_bf, w1_bf, b1, h_bf, tbl, ntp, H, D,
      w2, w2_bf, (long)E * D * H, maxTiles);
  // GEMM2: [T,H] x [E,D,H] -> out [T,D] f32, direct.
  dim3 g2(D / BN, maxTiles);
  grouped_gemm<0, 0, 0><<<g2, 256, 0, stream>>>(
      h_bf, w2_bf, b2, d_out, tbl, ntp, D, H,
      nullptr, nullptr, 0, maxTiles);
}

// Round 13
// 306.211 us; speedup vs baseline: 1.4934x; 1.0806x over previous
//
#include <hip/hip_runtime.h>
#include <hip/hip_bf16.h>
#include <cstdint>
#include <cstddef>

// MoE expert FFN: h = gelu(x @ w1[e]^T + b1[e]); out = h @ w2[e]^T + b2[e]
// R13: R12 locked config + ONE isolated probe:
//   GEMM2 BK=32 -> BK=64 (plain 2-buffer loop, 64KB LDS). GEMM2's grid
//   (512 blocks) already caps it at 2 blocks/CU, so the LDS doubling is free
//   there (m132's BK=128 regression was the 3->2 blocks/CU cliff, not BK
//   itself). Tests whether the ~1050cy/step non-MFMA overhead is
//   fixed-per-barrier (-> ~0.7x time) or byte-scaled (-> tie, floor declared).
//   GEMM1 = R12-exact control (BK=32 + cvt(w2) piggyback, ~166us).
// Also: build_tiles merged into the cvt dispatch (one fewer launch).

typedef __bf16 bf16x8 __attribute__((ext_vector_type(8)));
typedef float f32x4 __attribute__((ext_vector_type(4)));
typedef unsigned short u16x8 __attribute__((ext_vector_type(8)));

#define BM 128
#define BN 128

__device__ __forceinline__ unsigned short f2bf(float f) {
  unsigned u = __builtin_bit_cast(unsigned, f);
  u += 0x7FFFu + ((u >> 16) & 1u);   // RNE
  return (unsigned short)(u >> 16);
}

__device__ __forceinline__ float fast_gelu(float v) {
  const float u = 0.7978845608028654f * (v + 0.044715f * v * v * v);
  const float t = 1.0f - 2.0f / (__expf(2.0f * u) + 1.0f);   // tanh(u)
  return 0.5f * v * (1.0f + t);
}

__device__ __forceinline__ void gload16(const void* g, void* lds) {
  __builtin_amdgcn_global_load_lds(
      (const __attribute__((address_space(1))) void*)g,
      (__attribute__((address_space(3))) void*)lds, 16, 0, 0);
}

__device__ __forceinline__ void cvt8(const float* __restrict__ src,
                                     unsigned short* __restrict__ dst, long i) {
  float4 a = *reinterpret_cast<const float4*>(src + i);
  float4 b = *reinterpret_cast<const float4*>(src + i + 4);
  u16x8 o;
  o[0] = f2bf(a.x); o[1] = f2bf(a.y); o[2] = f2bf(a.z); o[3] = f2bf(a.w);
  o[4] = f2bf(b.x); o[5] = f2bf(b.y); o[6] = f2bf(b.z); o[7] = f2bf(b.w);
  *reinterpret_cast<u16x8*>(dst + i) = o;
}

// ------- cvt(inp)+cvt(w1) + tile-table build, one dispatch -------------------
__global__ void cvt2_build(const float* __restrict__ s0,
                           unsigned short* __restrict__ d0, long n0,
                           const float* __restrict__ s1,
                           unsigned short* __restrict__ d1, long n1,
                           const int* __restrict__ cnt, int E,
                           int4* __restrict__ tbl, int* __restrict__ ntp) {
  if (blockIdx.x == 0 && threadIdx.x == 0) {
    int nt = 0, start = 0;
    for (int e = 0; e < E; ++e) {
      int c = cnt[e];
      for (int t = 0; t < c; t += BM) {
        int4 v; v.x = e; v.y = start + t; v.z = (c - t < BM ? c - t : BM); v.w = 0;
        tbl[nt++] = v;
      }
      start += c;
    }
    *ntp = nt;
  }
  long i = ((long)blockIdx.x * blockDim.x + threadIdx.x) * 8;
  const long stride = (long)gridDim.x * blockDim.x * 8;
  const long ntot = n0 + n1;
  for (; i < ntot; i += stride) {
    if (i < n0) cvt8(s0, d0, i);
    else        cvt8(s1, d1, i - n0);
  }
}

// ---------------- grouped GEMM (R8 core, BKT templated, opt piggyback) -------
// C[t,n] = A[t,:] . W[e][n,:] (+bias, opt gelu). A:[T,K] bf16, W:[E,N,K] bf16.
template <int GELU, int OUTBF, int PIGGY, int BKT>
__global__ __launch_bounds__(256, 2) void grouped_gemm(
    const unsigned short* __restrict__ A, const unsigned short* __restrict__ W,
    const float* __restrict__ bias, void* __restrict__ Cv,
    const int4* __restrict__ tbl, const int* __restrict__ ntp,
    const int N, const int K,
    const float* __restrict__ pg_src, unsigned short* __restrict__ pg_dst,
    const long pg_n, const int yTiles) {
  if (PIGGY && (int)blockIdx.y >= yTiles) {
    // cvt piggyback in GEMM1's idle BW (R12: absorbed the standalone pass).
    const int p = ((int)blockIdx.y - yTiles) * gridDim.x + blockIdx.x;
    const long PB = (long)(gridDim.y - yTiles) * gridDim.x;
    long i = ((long)p * blockDim.x + threadIdx.x) * 8;
    const long stride = PB * blockDim.x * 8;
    for (; i < pg_n; i += stride) cvt8(pg_src, pg_dst, i);
    return;
  }

  const int mt = blockIdx.y;
  const int bx = blockIdx.x;
  if (mt >= *ntp) return;
  const int4 ti = tbl[mt];
  const int e = ti.x, row0 = ti.y, rows = ti.z;
  const int bcol = bx * BN;

  __shared__ alignas(16) unsigned short sA[2][BM * BKT];
  __shared__ alignas(16) unsigned short sB[2][BN * BKT];

  const int tid = threadIdx.x;
  const int lane = tid & 63;
  const int wave = tid >> 6;
  const int wr = wave >> 1;  // 0..1
  const int wc = wave & 1;   // 0..1
  const int lr = lane & 15;
  const int lhi = lane >> 4; // 0..3

  const unsigned short* __restrict__ Wexp = W + (size_t)e * N * K;

  // ---- staging geometry (dest linear: wave*1024 + lane*16 + i*4096) --------
  constexpr int CH  = BKT / 8;     // 16B chunks per row (4 or 8)
  constexpr int LPM = BKT / 16;    // gload16 per matrix per thread (2 or 4)
  constexpr int RPL = 2048 / BKT;  // rows per load-block (64 or 32)
  const int srow = wave * (512 / BKT) + (BKT == 32 ? (lane >> 2) : (lane >> 3));
  const int chn = lane & (CH - 1);
  int cg;                          // source chunk (inverse swizzle, const/thread)
  if constexpr (BKT == 32) cg = chn ^ ((srow >> 1) & 3);
  else                     cg = chn ^ (srow & 7);

  const unsigned short* gA[LPM];
  const unsigned short* gB[LPM];
#pragma unroll
  for (int i = 0; i < LPM; ++i) {
    const int rA = srow + i * RPL;
    const int rc = rA < rows ? rA : rows - 1;     // clamp inside segment
    gA[i] = A + (size_t)(row0 + rc) * K + cg * 8;
    gB[i] = Wexp + (size_t)(bcol + srow + i * RPL) * K + cg * 8;
  }

  auto stage = [&](int kt, int b) {
    char* da = (char*)&sA[b][0] + wave * 1024;
    char* db = (char*)&sB[b][0] + wave * 1024;
#pragma unroll
    for (int i = 0; i < LPM; ++i) {
      gload16(gA[i] + kt * BKT, da + i * 4096);
      gload16(gB[i] + kt * BKT, db + i * 4096);
    }
  };

  // ---- LDS read addressing (swizzled; conflict-free per quarter-wave) ------
  constexpr int KH = BKT / 32;     // 16x16x32 MFMAs per frag-row per step
  int swo[KH];
  if constexpr (BKT == 32) {
    swo[0] = (lhi ^ ((lr >> 1) & 3)) * 8;
  } else {
    swo[0] = (lhi ^ (lr & 7)) * 8;
    swo[1] = ((4 | lhi) ^ (lr & 7)) * 8;
  }
  const int aRowB = wr * 64 + lr;
  const int bRowB = wc * 64 + lr;

  f32x4 acc[4][4] = {};
  const int nk = K / BKT;

  stage(0, 0);
  __syncthreads();

  int buf = 0;
  for (int t = 0; t < nk; ++t) {
    if (t + 1 < nk) stage(t + 1, buf ^ 1);
    bf16x8 af[4][KH], bfr[4][KH];
#pragma unroll
    for (int m = 0; m < 4; ++m) {
      const unsigned short* rp = &sA[buf][(aRowB + m * 16) * BKT];
#pragma unroll
      for (int kh = 0; kh < KH; ++kh)
        af[m][kh] = *reinterpret_cast<const bf16x8*>(rp + swo[kh]);
    }
#pragma unroll
    for (int n = 0; n < 4; ++n) {
      const unsigned short* rp = &sB[buf][(bRowB + n * 16) * BKT];
#pragma unroll
      for (int kh = 0; kh < KH; ++kh)
        bfr[n][kh] = *reinterpret_cast<const bf16x8*>(rp + swo[kh]);
    }
#pragma unroll
    for (int kh = 0; kh < KH; ++kh)
#pragma unroll
      for (int m = 0; m < 4; ++m)
#pragma unroll
        for (int n = 0; n < 4; ++n)
          acc[m][n] = __builtin_amdgcn_mfma_f32_16x16x32_bf16(
              af[m][kh], bfr[n][kh], acc[m][n], 0, 0, 0);
    __syncthreads();
    buf ^= 1;
  }

  // Epilogue. C/D layout (m89): col = lane&15, row = (lane>>4)*4 + reg.
  const float* __restrict__ be = bias + (size_t)e * N;
  const int colBase = bcol + wc * 64 + lr;
  const int rowBase = wr * 64 + (lhi << 2);
#pragma unroll
  for (int n = 0; n < 4; ++n) {
    const int col = colBase + n * 16;
    const float bv = be[col];
#pragma unroll
    for (int m = 0; m < 4; ++m) {
      const int r0 = rowBase + m * 16;
#pragma unroll
      for (int j = 0; j < 4; ++j) {
        const int rr = r0 + j;
        if (rr < rows) {
          float v = acc[m][n][j] + bv;
          if (GELU) v = fast_gelu(v);
          const size_t idx = (size_t)(row0 + rr) * N + col;
          if (OUTBF) ((unsigned short*)Cv)[idx] = f2bf(v);
          else       ((float*)Cv)[idx] = v;
        }
      }
    }
  }
}

extern "C" void kernel_launch(void* const* d_in, const int* in_sizes, int n_in,
                              void* d_out, int out_size, void* d_ws, size_t ws_size,
                              hipStream_t stream) {
  const float* inp = (const float*)d_in[0];
  const float* w1  = (const float*)d_in[1];
  const float* b1  = (const float*)d_in[2];
  const float* w2  = (const float*)d_in[3];
  const float* b2  = (const float*)d_in[4];
  const int*   cnt = (const int*)d_in[5];

  const int E = in_sizes[5];
  const int H = in_sizes[2] / E;       // b1 is [E,H]
  const int D = in_sizes[4] / E;       // b2 is [E,D]
  const int T = in_sizes[0] / D;       // inp is [T,D]

  char* ws = (char*)d_ws;
  int4* tbl = (int4*)ws;               // <= 72 entries
  int* ntp = (int*)(ws + 2048);
  size_t off = 4096;
  unsigned short* inp_bf = (unsigned short*)(ws + off); off += (size_t)T * D * 2;
  unsigned short* w1_bf  = (unsigned short*)(ws + off); off += (size_t)E * H * D * 2;
  unsigned short* w2_bf  = (unsigned short*)(ws + off); off += (size_t)E * D * H * 2;
  unsigned short* h_bf   = (unsigned short*)(ws + off); off += (size_t)T * H * 2;
  (void)ws_size; (void)n_in; (void)out_size;

  // cvt(inp)+cvt(w1) + tile-table build, one dispatch (GEMM1 deps).
  cvt2_build<<<2048, 256, 0, stream>>>(inp, inp_bf, (long)T * D,
                                       w1, w1_bf, (long)E * H * D,
                                       cnt, E, tbl, ntp);

  const int maxTiles = T / BM + E;
  // GEMM1 (control, R12-exact): BK=32, piggyback cvt(w2) in 8 extra y-rows.
  dim3 g1(H / BN, maxTiles + 8);
  grouped_gemm<1, 1, 1, 32><<<g1, 256, 0, stream>>>(
      inp_bf, w1_bf, b1, h_bf, tbl, ntp, H, D,
      w2, w2_bf, (long)E * D * H, maxTiles);
  // GEMM2 (probe): BK=64 (2 blocks/CU already grid-capped -> LDS cost free).
  dim3 g2(D / BN, maxTiles);
  grouped_gemm<0, 0, 0, 64><<<g2, 256, 0, stream>>>(
      h_bf, w2_bf, b2, d_out, tbl, ntp, D, H,
      nullptr, nullptr, 0, maxTiles);
}